// Round 14
// baseline (112.783 us; speedup 1.0000x reference)
//
#include <hip/hip_runtime.h>

// Problem constants
#define NROWS 8192   // 4 * 2048
#define DIM   512
#define NT    64                    // 128-row tiles per side
#define NJT   32                    // 256-col super-tiles per side
#define NBLK  1056                  // sum_{bi} (NJT - bi/2): tiles touching j>=i
#define NACC  64                    // accumulator slots (contention spread)

using f32x4 = __attribute__((ext_vector_type(4))) float;

typedef __attribute__((address_space(1))) const void* as1_cvptr;
typedef __attribute__((address_space(3))) void*       as3_vptr;

// async global->LDS DMA, 16B per lane; LDS dest = wave-uniform base + lane*16
__device__ __forceinline__ void async16(const void* g, void* l) {
    __builtin_amdgcn_global_load_lds((as1_cvptr)g, (as3_vptr)l, 16, 0, 0);
}

// Software fp32 -> OCP e4m3fn, round-to-nearest-even (r7-r13-verified).
__device__ __forceinline__ unsigned char f2e4m3(float x) {
    unsigned ux = __float_as_uint(x);
    unsigned s  = (ux >> 24) & 0x80u;
    float a = __uint_as_float(ux & 0x7FFFFFFFu);     // |x|, finite for our data
    a = fminf(a, 448.0f);                            // clamp to max finite
    unsigned ua = __float_as_uint(a);
    int eb = (int)(ua >> 23);                        // biased exponent
    if (eb < 121) eb = 121;                          // denormal region: step 2^-9
    float step  = __uint_as_float((unsigned)(eb - 3) << 23);    // 2^(eb-130)
    float istep = __uint_as_float((unsigned)(257 - eb) << 23);  // 2^(130-eb), exact
    float q = rintf(a * istep) * step;               // RNE on e4m3 grid
    q = fminf(q, 448.0f);
    if (q < 0.001953125f)                            // below min denormal 2^-9 -> 0
        return (unsigned char)s;
    unsigned uq = __float_as_uint(q);
    int eq = (int)(uq >> 23) - 127;
    unsigned byte;
    if (eq < -6) byte = (unsigned)(q * 512.0f);      // denormal: d*2^-9, d in 1..7
    else         byte = (unsigned)((eq + 7) << 3) | ((uq >> 20) & 7u);
    return (unsigned char)(s | byte);
}

// Kernel 1 (r10-verified, unchanged): fp32 row norms + fp32->fp8 conversion
// into the pre-swizzled global layout: in each 64B k-slab of row r, 8B chunk
// c sits at position c ^ ((r>>1)&7) (measured 0 LDS conflicts in the GEMM).
__global__ __launch_bounds__(256) void norm_convert_kernel(
    const float* __restrict__ X, unsigned char* __restrict__ Xq,
    float* __restrict__ norms, float* __restrict__ acc)
{
    const int tid  = threadIdx.x;
    const int lane = tid & 63;
    const int w    = tid >> 6;
    const int row  = blockIdx.x * 4 + w;

    if (blockIdx.x == 0 && tid < NACC) acc[tid] = 0.0f;

    const float* xr = X + (size_t)row * DIM + lane * 8;
    float4 v0 = *(const float4*)xr;
    float4 v1 = *(const float4*)(xr + 4);

    float s = 0.0f;
    s = fmaf(v0.x, v0.x, s); s = fmaf(v0.y, v0.y, s);
    s = fmaf(v0.z, v0.z, s); s = fmaf(v0.w, v0.w, s);
    s = fmaf(v1.x, v1.x, s); s = fmaf(v1.y, v1.y, s);
    s = fmaf(v1.z, v1.z, s); s = fmaf(v1.w, v1.w, s);

    union { unsigned char b[8]; uint2 v; } pk;
    pk.b[0] = f2e4m3(v0.x); pk.b[1] = f2e4m3(v0.y);
    pk.b[2] = f2e4m3(v0.z); pk.b[3] = f2e4m3(v0.w);
    pk.b[4] = f2e4m3(v1.x); pk.b[5] = f2e4m3(v1.y);
    pk.b[6] = f2e4m3(v1.z); pk.b[7] = f2e4m3(v1.w);

    const int slab = lane >> 3;                        // 64B slab index (0..7)
    const int cpos = (lane & 7) ^ ((row >> 1) & 7);    // swizzled 8B position
    *(uint2*)(Xq + (size_t)row * DIM + slab * 64 + cpos * 8) = pk.v;

    #pragma unroll
    for (int off = 32; off > 0; off >>= 1) s += __shfl_down(s, off, 64);
    if (lane == 0) norms[row] = s;
}

// Kernel 2: 128x256 tile/block (8 waves of 64x64), fp8 e4m3 MFMA, BK=64,
// r10's verified DMA double-buffer pipeline.
//
// Rationale (r11-r13 post-mortems): VGPR caps occupancy at 16 waves/CU;
// r10 reaches it and every lower-residency variant (3-buf, K-resident,
// MX-64KB) measured 52-57 vs r10's 44.7. At FIXED registers+occupancy the
// open axis is work per output: the 128x256 tile stages A once for two
// j-tiles -> staged bytes & DMA instrs per output -25%, barriers per
// output -50%; LDS frag reads and MFMA per output unchanged. 2 blocks/CU
// (48KB LDS, 8 waves) = same 16 waves/CU as r10.
//
// Upper-triangle cover: (bi, J) for J >= bi>>1 (1056 blocks, +1.5% straddle
// waste). Per-element weight in epilogue: gj>gi -> 2x, else 0; the exact
// diagonal contribution (8192 terms of 1.0) is added in finalize.
// Swizzle/addressing identical to r10 (measured 0 conflicts).
// NO device-scope fences (r3); no raw-asm barriers (r11).
__global__ __launch_bounds__(512, 4) void pair_loss_gemm_kernel(
    const unsigned char* __restrict__ Xq, const float* __restrict__ norms,
    float* __restrict__ acc)
{
    __shared__ __align__(16) char As[2][8192];    // 128 rows x 64B
    __shared__ __align__(16) char Bs[2][16384];   // 256 cols x 64B
    __shared__ float wsum[8];

    // decode linear block id -> (bi, J), J >= bi>>1
    int t = blockIdx.x, bi = 0;
    while (t >= (NJT - (bi >> 1))) { t -= (NJT - (bi >> 1)); bi++; }
    const int J = (bi >> 1) + t;

    const int tid  = threadIdx.x;
    const int lane = tid & 63;
    const int w    = tid >> 6;          // 0..7

    const int rowA = bi * 128;
    const int colB = J * 256;

    f32x4 accv[4][4];
    const f32x4 zero = {0.0f, 0.0f, 0.0f, 0.0f};
    #pragma unroll
    for (int a = 0; a < 4; a++)
        #pragma unroll
        for (int b = 0; b < 4; b++) accv[a][b] = zero;

    // DMA staging per iter: A = 512 16B-chunks (1 instr/wave), B = 1024
    // (2 instrs/wave). Chunk ci -> row ci>>2, 16B piece ci&3; LDS linear.
    const int ciA = w * 64 + lane;
    const unsigned char* gA =
        Xq + (size_t)(rowA + (ciA >> 2)) * DIM + (ciA & 3) * 16;
    const int ciB0 = w * 128 + lane;          // B chunk for instr n=0; n=1: +64
    const unsigned char* gB0 =
        Xq + (size_t)(colB + (ciB0 >> 2)) * DIM + (ciB0 & 3) * 16;
    const unsigned char* gB1 = gB0 + (size_t)16 * DIM;   // +64 chunks = +16 rows
    const int lA = w * 1024;                  // wave-uniform LDS bases
    const int lB = w * 2048;

    // MFMA fp8 frag (r10-identical): lane (fr=lane&15, q=lane>>4) reads 8B at
    // row*64 + ((kstep*4+q)^((fr>>1)&7))*8; kstep1 offset = fo0 ^ 32.
    const int fr  = lane & 15;
    const int q   = lane >> 4;
    const int fo0 = fr * 64 + ((q ^ ((fr >> 1) & 7)) * 8);
    const int wr  = (w & 1) * 64;             // A quadrant row base (0/64)
    const int wc  = (w >> 1) * 64;            // B quadrant col base (0..192)

    // prologue: DMA slab 0 into buffer 0
    async16(gA,  As[0] + lA);
    async16(gB0, Bs[0] + lB);
    async16(gB1, Bs[0] + lB + 1024);
    __syncthreads();

    #pragma unroll 1
    for (int k = 0; k < 8; k++) {
        const int cur = k & 1;
        const char* curA = As[cur];
        const char* curB = Bs[cur];

        long afr[2][4], bfr[2][4];
        #pragma unroll
        for (int s = 0; s < 2; s++) {
            const int fo = fo0 ^ (s << 5);
            #pragma unroll
            for (int a = 0; a < 4; a++)
                afr[s][a] = *(const long*)(curA + (wr + a * 16) * 64 + fo);
            #pragma unroll
            for (int b = 0; b < 4; b++)
                bfr[s][b] = *(const long*)(curB + (wc + b * 16) * 64 + fo);
        }

        // DMA next slab into the other buffer; lands during the 32 MFMAs
        const bool more = (k < 7);
        if (more) {
            const int nxt = cur ^ 1;
            const int k0  = (k + 1) * 64;
            async16(gA  + k0, As[nxt] + lA);
            async16(gB0 + k0, Bs[nxt] + lB);
            async16(gB1 + k0, Bs[nxt] + lB + 1024);
        }

        #pragma unroll
        for (int s = 0; s < 2; s++)
            #pragma unroll
            for (int a = 0; a < 4; a++)
                #pragma unroll
                for (int b = 0; b < 4; b++)
                    accv[a][b] = __builtin_amdgcn_mfma_f32_16x16x32_fp8_fp8(
                        afr[s][a], bfr[s][b], accv[a][b], 0, 0, 0);

        if (more) __syncthreads();
    }

    // epilogue: term = exp(-0.1*sqrt(max(ni+nj-2*dot,0))); weight 2 if gj>gi
    // (strict upper triangle), 0 otherwise; diagonal (+8192 exact) added in
    // finalize. C/D layout: col = lane&15, row = (lane>>4)*4 + reg.
    float lsum = 0.0f;
    #pragma unroll
    for (int a = 0; a < 4; a++) {
        const int gi0 = rowA + wr + a * 16 + q * 4;
        #pragma unroll
        for (int b = 0; b < 4; b++) {
            const int gj = colB + wc + b * 16 + fr;
            const float nj = norms[gj];
            #pragma unroll
            for (int r = 0; r < 4; r++) {
                const int gi = gi0 + r;
                float sq = fmaf(-2.0f, accv[a][b][r], norms[gi] + nj);
                sq = fmaxf(sq, 0.0f);
                float term = __expf(-0.1f * sqrtf(sq));
                lsum += (gj > gi) ? 2.0f * term : 0.0f;
            }
        }
    }
    #pragma unroll
    for (int off = 32; off > 0; off >>= 1) lsum += __shfl_down(lsum, off, 64);
    if (lane == 0) wsum[w] = lsum;
    __syncthreads();
    if (tid == 0) {
        float bsum = 0.0f;
        #pragma unroll
        for (int i = 0; i < 8; i++) bsum += wsum[i];
        atomicAdd(&acc[blockIdx.x & (NACC - 1)], bsum);
    }
}

// Kernel 3: finalize (sum NACC slots + exact diagonal 8192)
__global__ void finalize_kernel(const float* __restrict__ acc,
                                float* __restrict__ out)
{
    const int lane = threadIdx.x;
    float s = (lane < NACC) ? acc[lane] : 0.0f;
    #pragma unroll
    for (int off = 32; off > 0; off >>= 1) s += __shfl_down(s, off, 64);
    if (lane == 0) {
        const float inv = 1.0f / ((float)NROWS * (float)NROWS); // 2^-26 exact
        float loss = (s + 8192.0f) * inv * 0.1f;
        out[0] = loss;
        out[1] = 0.5f * loss;
    }
}

extern "C" void kernel_launch(void* const* d_in, const int* in_sizes, int n_in,
                              void* d_out, int out_size, void* d_ws, size_t ws_size,
                              hipStream_t stream)
{
    const float* X = (const float*)d_in[0];
    float* out = (float*)d_out;

    char* ws = (char*)d_ws;
    float*         acc   = (float*)ws;                   // NACC fp32 slots
    float*         norms = (float*)(ws + 1024);          // 8192 fp32 (32 KB)
    unsigned char* Xq    = (unsigned char*)(ws + 1024 + 32768); // fp8 X, 4 MB

    norm_convert_kernel<<<NROWS / 4, 256, 0, stream>>>(X, Xq, norms, acc);
    pair_loss_gemm_kernel<<<NBLK, 512, 0, stream>>>(Xq, norms, acc);
    finalize_kernel<<<1, 64, 0, stream>>>(acc, out);
}